// Round 3
// baseline (516.260 us; speedup 1.0000x reference)
//
#include <hip/hip_runtime.h>
#include <cmath>

#define BB 4
#define LL 2048
#define DD 1024
#define HH 8
#define MM (BB * LL)   // 8192 rows

struct Gammas { float lg2[8]; };
struct MMArgs { const ushort* Bt[4]; void* C[4]; int emode[4]; };

typedef __attribute__((ext_vector_type(8))) short bf16x8;
typedef __attribute__((ext_vector_type(4))) float f32x4;

__device__ __forceinline__ ushort f2bf(float f) {
    uint u = __builtin_bit_cast(uint, f);
    uint r = (u + 0x7fffu + ((u >> 16) & 1u)) >> 16;
    return (ushort)r;
}
__device__ __forceinline__ float bf2f(ushort h) {
    uint u = ((uint)h) << 16;
    return __builtin_bit_cast(float, u);
}
__device__ __forceinline__ void gload16(const void* g, void* l) {
    __builtin_amdgcn_global_load_lds((const __attribute__((address_space(1))) void*)g,
                                     (__attribute__((address_space(3))) void*)l, 16, 0, 0);
}

// ---------------------------------------------------------------------------
// xpos table: tbl[l*64 + i] = {cos*scale, sin*scale, cos/scale, sin/scale}
// ---------------------------------------------------------------------------
__global__ void xpos_table_kernel(float4* __restrict__ tbl) {
    int tid = blockIdx.x * blockDim.x + threadIdx.x;
    if (tid >= LL * 64) return;
    int l = tid >> 6, i = tid & 63;
    float inv = powf(10000.0f, -(float)i / 64.0f);
    float ang = (float)l * inv;
    float s = sinf(ang), c = cosf(ang);
    float base = (2.0f * (float)i + 51.2f) / 179.2f;
    float sc = powf(base, (float)l / 512.0f);
    tbl[tid] = make_float4(c * sc, s * sc, c / sc, s / sc);
}

__global__ __launch_bounds__(256) void cast_kernel(const float* __restrict__ X,
                                                   ushort* __restrict__ Xb) {
    int i = (blockIdx.x * 256 + threadIdx.x) * 4;
    float4 v = *(const float4*)&X[i];
    ushort4 o;
    o.x = f2bf(v.x); o.y = f2bf(v.y); o.z = f2bf(v.z); o.w = f2bf(v.w);
    *(ushort4*)&Xb[i] = o;
}

// ---------------------------------------------------------------------------
// Weight transpose+cast: W[k][n] (flat or per-head (h,d,e)) -> Wt[n][k] bf16
// ---------------------------------------------------------------------------
__global__ __launch_bounds__(256) void wtrans_kernel(const float* __restrict__ W,
                                                     ushort* __restrict__ Wt, int perhead) {
    __shared__ float T[64][68];
    const int k0 = blockIdx.y * 64, n0 = blockIdx.x * 64;
    const int t = threadIdx.x;
    for (int f = t; f < 64 * 16; f += 256) {
        int kk = f >> 4, s = f & 15;
        int n = n0 + s * 4;
        size_t src = perhead ? (size_t)(n >> 7) * 131072 + (size_t)(k0 + kk) * 128 + (n & 127)
                             : (size_t)(k0 + kk) * 1024 + n;
        *(float4*)&T[kk][s * 4] = *(const float4*)&W[src];
    }
    __syncthreads();
    for (int f = t; f < 64 * 8; f += 256) {
        int n = f >> 3, s = f & 7;
        __align__(16) ushort tmp[8];
        #pragma unroll
        for (int j = 0; j < 8; j++) tmp[j] = f2bf(T[s * 8 + j][n]);
        *(uint4*)&Wt[(size_t)(n0 + n) * 1024 + k0 + s * 8] = *(uint4*)tmp;
    }
}

// ---------------------------------------------------------------------------
// bf16 MFMA GEMM, 256x256 tile, 512 threads (8 waves, 2M x 4N), BK=64 as
// two K=32 planes (64B LDS rows -> benign bank pattern, linear gload_lds
// dests). 2-phase double-buffered pipeline, one barrier per K-step.
// emode: 1 xpos up->bf16, 2 xpos down->bf16, 3 silu->bf16, 4 plain->fp32,
//        5 V-transposed store (Vt[b][v][l] bf16)
// ---------------------------------------------------------------------------
__global__ __launch_bounds__(512) void mm_kernel(
    const ushort* __restrict__ A, MMArgs args, const float4* __restrict__ tbl)
{
    // [buf][plane][256 rows x 32 cols]  : 2*2*8192*2B*2(A,B) = 128 KB
    __shared__ __align__(16) ushort As[2][2][256 * 32];
    __shared__ __align__(16) ushort Bs[2][2][256 * 32];

    const int t = threadIdx.x;
    const int w = t >> 6, lane = t & 63;
    const int ln = lane & 15, quad = lane >> 4;
    const int which = blockIdx.x >> 2;
    const ushort* Bt = args.Bt[which];
    void* Cv = args.C[which];
    const int emode = args.emode[which];
    const int n0 = (blockIdx.x & 3) * 256, m0 = blockIdx.y * 256;
    const int wm = w & 1, wn = w >> 1;    // wave tile: 128 rows x 64 cols

    f32x4 acc[8][4];
    const f32x4 fzero = {0.f, 0.f, 0.f, 0.f};
    #pragma unroll
    for (int i = 0; i < 8; i++)
        #pragma unroll
        for (int j = 0; j < 4; j++) acc[i][j] = fzero;

    // staging: wave w covers rows [i*128 + w*16, +16) of the tile, per plane
    const int srow = lane >> 2;           // 0..15
    const int scol = (lane & 3) * 8;      // 0,8,16,24
    const ushort* gA = A  + (size_t)(m0 + w * 16 + srow) * 1024 + scol;
    const ushort* gB = Bt + (size_t)(n0 + w * 16 + srow) * 1024 + scol;

    auto stage = [&](int buf, int kt) {
        #pragma unroll
        for (int i = 0; i < 2; i++) {
            #pragma unroll
            for (int p = 0; p < 2; p++) {
                gload16(gA + (size_t)i * 128 * 1024 + kt + p * 32,
                        &As[buf][p][(i * 128 + w * 16) * 32]);
                gload16(gB + (size_t)i * 128 * 1024 + kt + p * 32,
                        &Bs[buf][p][(i * 128 + w * 16) * 32]);
            }
        }
    };

    stage(0, 0);
    __syncthreads();

    for (int kt = 0; kt < 1024; kt += 64) {
        const int cur = (kt >> 6) & 1;
        if (kt < 1024 - 64) stage(cur ^ 1, kt + 64);
        #pragma unroll
        for (int kk = 0; kk < 2; kk++) {
            bf16x8 am[8], bn[4];
            #pragma unroll
            for (int mi = 0; mi < 8; mi++)
                am[mi] = *(const bf16x8*)&As[cur][kk][(wm * 128 + mi * 16 + ln) * 32 + quad * 8];
            #pragma unroll
            for (int ni = 0; ni < 4; ni++)
                bn[ni] = *(const bf16x8*)&Bs[cur][kk][(wn * 64 + ni * 16 + ln) * 32 + quad * 8];
            #pragma unroll
            for (int mi = 0; mi < 8; mi++)
                #pragma unroll
                for (int ni = 0; ni < 4; ni++)
                    acc[mi][ni] = __builtin_amdgcn_mfma_f32_16x16x32_bf16(
                        am[mi], bn[ni], acc[mi][ni], 0, 0, 0);
        }
        __syncthreads();
    }

    #pragma unroll
    for (int mi = 0; mi < 8; mi++) {
        #pragma unroll
        for (int ni = 0; ni < 4; ni++) {
            const int row0 = m0 + wm * 128 + mi * 16 + quad * 4;
            const int e = wn * 64 + ni * 16 + ln;       // col within block (0..255)
            const int col = n0 + e;                     // col within output (0..1023)
            if (emode == 5) {
                const int b = row0 >> 11, l0 = row0 & (LL - 1);
                ushort4 pk;
                pk.x = f2bf(acc[mi][ni][0]); pk.y = f2bf(acc[mi][ni][1]);
                pk.z = f2bf(acc[mi][ni][2]); pk.w = f2bf(acc[mi][ni][3]);
                *(ushort4*)&((ushort*)Cv)[((size_t)(b * 1024 + col)) * 2048 + l0] = pk;
                continue;
            }
            #pragma unroll
            for (int r = 0; r < 4; r++) {
                float v = acc[mi][ni][r];
                if (emode == 1 || emode == 2) {
                    float4 tt = tbl[(size_t)((row0 + r) & (LL - 1)) * 64 + ((col & 127) >> 1)];
                    float cc = (emode == 1) ? tt.x : tt.z;
                    float ss = (emode == 1) ? tt.y : tt.w;
                    float partner = __shfl_xor(v, 1);
                    float rot = (col & 1) ? partner : -partner;
                    v = v * cc + rot * ss;
                } else if (emode == 3) {
                    v = v / (1.0f + expf(-v));
                }
                if (emode == 4)
                    ((float*)Cv)[(size_t)(row0 + r) * 1024 + col] = v;
                else
                    ((ushort*)Cv)[(size_t)(row0 + r) * 1024 + col] = f2bf(v);
            }
        }
    }
}

// ---------------------------------------------------------------------------
// Retention (MFMA, balanced) + FUSED GroupNorm/gate epilogue.
// Block z handles query blocks z and 31-z of its (b,h). Each block holds the
// full 128-dim v-range for its 64 rows -> mean/var via in-quad shfl reduce,
// affine + silu-gate applied in registers, Z written bf16 directly.
// XCD swizzle: all 16 x-blocks of one (b,h) land on one XCD (K/V set = 4MB).
// ---------------------------------------------------------------------------
__global__ __launch_bounds__(256) void ret_kernel(
    const ushort* __restrict__ Qb, const ushort* __restrict__ Kb,
    const ushort* __restrict__ Vt, const ushort* __restrict__ Gb,
    const float* __restrict__ gnw, const float* __restrict__ gnb,
    ushort* __restrict__ Z, Gammas gp)
{
    __shared__ __align__(16) ushort Ks[64 * 136];
    __shared__ __align__(16) ushort Vs[128 * 72];
    __shared__ __align__(16) ushort Ss[64 * 72];

    const int t = threadIdx.x;
    const int w = t >> 6, lane = t & 63, ln = lane & 15, quad = lane >> 4;

    // XCD-aware swizzle (512 blocks, 512%8==0 -> bijective):
    // xcd = gid%8 gets bh in [4*xcd, 4*xcd+3], all 16 x-blocks of each.
    const int gid = blockIdx.y * 16 + blockIdx.x;
    const int xcd = gid & 7, within = gid >> 3;
    const int bh = (xcd << 2) | (within >> 4);
    const int xb = within & 15;

    const int b = bh >> 3, h = bh & 7;
    const float lg2 = gp.lg2[h];
    const size_t qkbase = (size_t)b * LL * 1024 + (size_t)h * 128;
    const size_t vtbase = ((size_t)b * 1024 + h * 128) * 2048;

    // decay cutoff: skip chunks where max decay < 2^-34
    const int cap = (int)((34.0f / (-lg2) + 63.0f) * 0.015625f);

    float dmk[4], drr[4];
    #pragma unroll
    for (int kt = 0; kt < 4; kt++)
        dmk[kt] = exp2f(-(float)(kt * 16 + quad * 4) * lg2);
    #pragma unroll
    for (int r = 0; r < 4; r++)
        drr[r] = exp2f(-(float)r * lg2);

    // groupnorm affine params (cols identical for both segs)
    float gwv[8], gbv[8];
    #pragma unroll
    for (int vt = 0; vt < 8; vt++) {
        gwv[vt] = gnw[h * 128 + vt * 16 + ln];
        gbv[vt] = gnb[h * 128 + vt * 16 + ln];
    }

    // staging indices
    const int krow = t >> 4, kc = (t & 15) * 8;      // K: 4 x (16-row step)
    const int vrow = t >> 3, vc = (t & 7) * 8;       // V: 4 x (32-row step)

    for (int seg = 0; seg < 2; seg++) {
        const int qb = seg ? 31 - xb : xb;
        const int n0 = qb * 64;

        bf16x8 aq[4];
        #pragma unroll
        for (int ks = 0; ks < 4; ks++)
            aq[ks] = *(const bf16x8*)&Qb[qkbase + (size_t)(n0 + 16 * w + ln) * 1024
                                         + ks * 32 + quad * 8];
        f32x4 y[8];
        const f32x4 fzero = {0.f, 0.f, 0.f, 0.f};
        #pragma unroll
        for (int vt = 0; vt < 8; vt++) y[vt] = fzero;

        int cmin = qb - cap; if (cmin < 0) cmin = 0;

        uint4 kreg[4], vreg[4];
        {
            const int m0 = cmin * 64;
            #pragma unroll
            for (int i = 0; i < 4; i++)
                kreg[i] = *(const uint4*)&Kb[qkbase + (size_t)(m0 + krow + i * 16) * 1024 + kc];
            #pragma unroll
            for (int i = 0; i < 4; i++)
                vreg[i] = *(const uint4*)&Vt[vtbase + (size_t)(vrow + i * 32) * 2048 + m0 + vc];
        }

        for (int c = cmin; c <= qb; c++) {
            const int m0 = c * 64;
            __syncthreads();
            #pragma unroll
            for (int i = 0; i < 4; i++)
                *(uint4*)&Ks[(krow + i * 16) * 136 + kc] = kreg[i];
            #pragma unroll
            for (int i = 0; i < 4; i++)
                *(uint4*)&Vs[(vrow + i * 32) * 72 + vc] = vreg[i];
            __syncthreads();
            if (c < qb) {
                const int m1 = m0 + 64;
                #pragma unroll
                for (int i = 0; i < 4; i++)
                    kreg[i] = *(const uint4*)&Kb[qkbase + (size_t)(m1 + krow + i * 16) * 1024 + kc];
                #pragma unroll
                for (int i = 0; i < 4; i++)
                    vreg[i] = *(const uint4*)&Vt[vtbase + (size_t)(vrow + i * 32) * 2048 + m1 + vc];
            }

            // S^T blocks: mfma(bk, aq) -> lane holds S[n=16w+ln][m=kt*16+quad*4+r]
            f32x4 s4[4];
            #pragma unroll
            for (int kt = 0; kt < 4; kt++) s4[kt] = fzero;
            #pragma unroll
            for (int ks = 0; ks < 4; ks++) {
                #pragma unroll
                for (int kt = 0; kt < 4; kt++) {
                    bf16x8 bk = *(const bf16x8*)&Ks[(kt * 16 + ln) * 136 + ks * 32 + quad * 8];
                    s4[kt] = __builtin_amdgcn_mfma_f32_16x16x32_bf16(bk, aq[ks], s4[kt], 0, 0, 0);
                }
            }

            const float dq = exp2f((float)(n0 - m0 + 16 * w + ln) * lg2);
            if (c == qb) {
                #pragma unroll
                for (int kt = 0; kt < 4; kt++) {
                    const float db = dq * dmk[kt];
                    ushort4 pk;
                    pk.x = f2bf((kt * 16 + quad * 4 + 0 <= 16 * w + ln) ? s4[kt][0] * db * drr[0] : 0.f);
                    pk.y = f2bf((kt * 16 + quad * 4 + 1 <= 16 * w + ln) ? s4[kt][1] * db * drr[1] : 0.f);
                    pk.z = f2bf((kt * 16 + quad * 4 + 2 <= 16 * w + ln) ? s4[kt][2] * db * drr[2] : 0.f);
                    pk.w = f2bf((kt * 16 + quad * 4 + 3 <= 16 * w + ln) ? s4[kt][3] * db * drr[3] : 0.f);
                    *(ushort4*)&Ss[(16 * w + ln) * 72 + kt * 16 + quad * 4] = pk;
                }
            } else {
                #pragma unroll
                for (int kt = 0; kt < 4; kt++) {
                    const float db = dq * dmk[kt];
                    ushort4 pk;
                    pk.x = f2bf(s4[kt][0] * db * drr[0]);
                    pk.y = f2bf(s4[kt][1] * db * drr[1]);
                    pk.z = f2bf(s4[kt][2] * db * drr[2]);
                    pk.w = f2bf(s4[kt][3] * db * drr[3]);
                    *(ushort4*)&Ss[(16 * w + ln) * 72 + kt * 16 + quad * 4] = pk;
                }
            }

            // Y += S * V   (Ss rows are wave-private: no barrier needed)
            #pragma unroll
            for (int ks2 = 0; ks2 < 2; ks2++) {
                bf16x8 as = *(const bf16x8*)&Ss[(16 * w + ln) * 72 + ks2 * 32 + quad * 8];
                #pragma unroll
                for (int vt = 0; vt < 8; vt++) {
                    bf16x8 bv = *(const bf16x8*)&Vs[(vt * 16 + ln) * 72 + ks2 * 32 + quad * 8];
                    y[vt] = __builtin_amdgcn_mfma_f32_16x16x32_bf16(as, bv, y[vt], 0, 0, 0);
                }
            }
        }

        // fused GroupNorm + affine + gate epilogue (row = n0+16w+quad*4+r,
        // its 128 v-values live in the 16 ln-lanes of this quad x 8 vt regs)
        #pragma unroll
        for (int r = 0; r < 4; r++) {
            float s = 0.f, sq = 0.f;
            #pragma unroll
            for (int vt = 0; vt < 8; vt++) {
                float v = y[vt][r];
                s += v; sq += v * v;
            }
            #pragma unroll
            for (int off = 8; off >= 1; off >>= 1) {
                s  += __shfl_xor(s, off, 64);
                sq += __shfl_xor(sq, off, 64);
            }
            float mean = s * 0.0078125f;
            float var = sq * 0.0078125f - mean * mean;
            float rstd = rsqrtf(var + 1e-5f);
            const size_t row = (size_t)(b * LL + n0 + 16 * w + quad * 4 + r);
            #pragma unroll
            for (int vt = 0; vt < 8; vt++) {
                float gv = bf2f(Gb[row * 1024 + h * 128 + vt * 16 + ln]);
                float o = (y[vt][r] - mean) * rstd * gwv[vt] + gbv[vt];
                Z[row * 1024 + h * 128 + vt * 16 + ln] = f2bf(o * gv);
            }
        }
    }
}

// ---------------------------------------------------------------------------
extern "C" void kernel_launch(void* const* d_in, const int* in_sizes, int n_in,
                              void* d_out, int out_size, void* d_ws, size_t ws_size,
                              hipStream_t stream) {
    const float* X   = (const float*)d_in[0];
    const float* Wq  = (const float*)d_in[1];
    const float* Wk  = (const float*)d_in[2];
    const float* Wv  = (const float*)d_in[3];
    const float* Wg  = (const float*)d_in[4];
    const float* Wo  = (const float*)d_in[5];
    const float* gnw = (const float*)d_in[6];
    const float* gnb = (const float*)d_in[7];
    float* out = (float*)d_out;

    const size_t MB = 1u << 20;
    char* base = (char*)d_ws;
    float4* tbl = (float4*)base;                        // 2 MB
    ushort* Xb  = (ushort*)(base + 2 * MB);             // 16 MB
    ushort* Wqt = (ushort*)(base + 18 * MB);
    ushort* Wkt = (ushort*)(base + 20 * MB);
    ushort* Wvt = (ushort*)(base + 22 * MB);
    ushort* Wgt = (ushort*)(base + 24 * MB);
    ushort* Wot = (ushort*)(base + 26 * MB);
    ushort* Qb  = (ushort*)(base + 28 * MB);            // 16 MB
    ushort* Kb  = (ushort*)(base + 44 * MB);            // 16 MB
    ushort* Gb  = (ushort*)(base + 60 * MB);            // 16 MB
    ushort* Vt  = (ushort*)(base + 76 * MB);            // 16 MB
    ushort* Zb  = (ushort*)(base + 92 * MB);            // 16 MB (own buffer:
                                                        // ret reads Qb concurrently)

    Gammas gp;
    for (int h = 0; h < 8; h++) {
        double lin = log(1.0 / 32.0) +
                     (log(1.0 / 512.0) - log(1.0 / 32.0)) * (double)h / 7.0;
        float gamma = 1.0f - expf((float)lin);
        gp.lg2[h] = log2f(gamma);
    }

    xpos_table_kernel<<<(LL * 64) / 256, 256, 0, stream>>>(tbl);
    cast_kernel<<<MM * 1024 / 1024, 256, 0, stream>>>(X, Xb);

    dim3 wgrid(16, 16);
    wtrans_kernel<<<wgrid, 256, 0, stream>>>(Wq, Wqt, 1);
    wtrans_kernel<<<wgrid, 256, 0, stream>>>(Wk, Wkt, 1);
    wtrans_kernel<<<wgrid, 256, 0, stream>>>(Wv, Wvt, 1);
    wtrans_kernel<<<wgrid, 256, 0, stream>>>(Wg, Wgt, 0);
    wtrans_kernel<<<wgrid, 256, 0, stream>>>(Wo, Wot, 0);

    // fused Q/K/V/G projections (V written directly transposed into Vt)
    // 256x256 tiles: x = which(4) * nblk(4), y = 8192/256 = 32
    MMArgs qa;
    qa.Bt[0] = Wqt; qa.Bt[1] = Wkt; qa.Bt[2] = Wvt; qa.Bt[3] = Wgt;
    qa.C[0] = Qb;   qa.C[1] = Kb;   qa.C[2] = Vt;   qa.C[3] = Gb;
    qa.emode[0] = 1; qa.emode[1] = 2; qa.emode[2] = 5; qa.emode[3] = 3;
    mm_kernel<<<dim3(16, 32), 512, 0, stream>>>(Xb, qa, tbl);

    // retention + fused groupnorm/gate -> Zb (bf16)
    ret_kernel<<<dim3(16, 32), 256, 0, stream>>>(Qb, Kb, Vt, Gb, gnw, gnb, Zb, gp);

    MMArgs oa;
    oa.Bt[0] = Wot; oa.Bt[1] = Wot; oa.Bt[2] = Wot; oa.Bt[3] = Wot;
    oa.C[0] = out;  oa.C[1] = out;  oa.C[2] = out;  oa.C[3] = out;
    oa.emode[0] = 4; oa.emode[1] = 4; oa.emode[2] = 4; oa.emode[3] = 4;
    mm_kernel<<<dim3(4, 32), 512, 0, stream>>>(Zb, oa, tbl);
}

// Round 4
// 491.732 us; speedup vs baseline: 1.0499x; 1.0499x over previous
//
#include <hip/hip_runtime.h>
#include <cmath>

#define BB 4
#define LL 2048
#define DD 1024
#define HH 8
#define MM (BB * LL)   // 8192 rows

struct Gammas { float lg2[8]; };
struct MMArgs { const ushort* Bt[4]; void* C[4]; int emode[4]; };

typedef __attribute__((ext_vector_type(8))) short bf16x8;
typedef __attribute__((ext_vector_type(4))) float f32x4;

__device__ __forceinline__ ushort f2bf(float f) {
    uint u = __builtin_bit_cast(uint, f);
    uint r = (u + 0x7fffu + ((u >> 16) & 1u)) >> 16;
    return (ushort)r;
}
__device__ __forceinline__ float bf2f(ushort h) {
    uint u = ((uint)h) << 16;
    return __builtin_bit_cast(float, u);
}
__device__ __forceinline__ void gload16(const void* g, void* l) {
    __builtin_amdgcn_global_load_lds((const __attribute__((address_space(1))) void*)g,
                                     (__attribute__((address_space(3))) void*)l, 16, 0, 0);
}

// ---------------------------------------------------------------------------
// xpos table: tbl[l*64 + i] = {cos*scale, sin*scale, cos/scale, sin/scale}
// ---------------------------------------------------------------------------
__global__ void xpos_table_kernel(float4* __restrict__ tbl) {
    int tid = blockIdx.x * blockDim.x + threadIdx.x;
    if (tid >= LL * 64) return;
    int l = tid >> 6, i = tid & 63;
    float inv = powf(10000.0f, -(float)i / 64.0f);
    float ang = (float)l * inv;
    float s = sinf(ang), c = cosf(ang);
    float base = (2.0f * (float)i + 51.2f) / 179.2f;
    float sc = powf(base, (float)l / 512.0f);
    tbl[tid] = make_float4(c * sc, s * sc, c / sc, s / sc);
}

__global__ __launch_bounds__(256) void cast_kernel(const float* __restrict__ X,
                                                   ushort* __restrict__ Xb) {
    int i = (blockIdx.x * 256 + threadIdx.x) * 4;
    float4 v = *(const float4*)&X[i];
    ushort4 o;
    o.x = f2bf(v.x); o.y = f2bf(v.y); o.z = f2bf(v.z); o.w = f2bf(v.w);
    *(ushort4*)&Xb[i] = o;
}

// ---------------------------------------------------------------------------
// Weight transpose+cast: W[k][n] (flat or per-head (h,d,e)) -> Wt[n][k] bf16
// ---------------------------------------------------------------------------
__global__ __launch_bounds__(256) void wtrans_kernel(const float* __restrict__ W,
                                                     ushort* __restrict__ Wt, int perhead) {
    __shared__ float T[64][68];
    const int k0 = blockIdx.y * 64, n0 = blockIdx.x * 64;
    const int t = threadIdx.x;
    for (int f = t; f < 64 * 16; f += 256) {
        int kk = f >> 4, s = f & 15;
        int n = n0 + s * 4;
        size_t src = perhead ? (size_t)(n >> 7) * 131072 + (size_t)(k0 + kk) * 128 + (n & 127)
                             : (size_t)(k0 + kk) * 1024 + n;
        *(float4*)&T[kk][s * 4] = *(const float4*)&W[src];
    }
    __syncthreads();
    for (int f = t; f < 64 * 8; f += 256) {
        int n = f >> 3, s = f & 7;
        __align__(16) ushort tmp[8];
        #pragma unroll
        for (int j = 0; j < 8; j++) tmp[j] = f2bf(T[s * 8 + j][n]);
        *(uint4*)&Wt[(size_t)(n0 + n) * 1024 + k0 + s * 8] = *(uint4*)tmp;
    }
}

// ---------------------------------------------------------------------------
// bf16 MFMA GEMM: C = A[8192x1024] * Bt^T, multi-output (4 weight/out sets).
// 128x128 tile, BK=32, TRIPLE-buffered LDS, ONE raw s_barrier per K-step,
// COUNTED s_waitcnt vmcnt(4): the 4 just-issued prefetch loads stay in
// flight across the barrier (no drain-to-0). Race-free: stage target
// (i+1)%3 never collides with iter i / i-1 readers; barrier i-1 separates
// it from iter i-2 readers.
// emode: 1 xpos up->bf16, 2 xpos down->bf16, 3 silu->bf16, 4 plain->fp32,
//        5 V-transposed store (Vt[b][v][l] bf16)
// ---------------------------------------------------------------------------
__global__ __launch_bounds__(256) void mm_kernel(
    const ushort* __restrict__ A, MMArgs args, const float4* __restrict__ tbl)
{
    __shared__ __align__(16) ushort As[3][128 * 32];
    __shared__ __align__(16) ushort Bs[3][128 * 32];
    const int t = threadIdx.x;
    const int w = t >> 6, lane = t & 63;
    const int ln = lane & 15, quad = lane >> 4;

    // XCD-chunked swizzle (bijective since nwg % 8 == 0): each XCD owns a
    // contiguous slab of y-strips -> A-strip reuse becomes L2-local.
    const int gx = gridDim.x;
    const int nwg = gx * gridDim.y;
    const int gid0 = blockIdx.y * gx + blockIdx.x;
    const int lin = (gid0 & 7) * (nwg >> 3) + (gid0 >> 3);
    const int bx = lin & (gx - 1);          // gx is a power of two (32 or 8)
    const int by = lin / gx;

    const int which = bx >> 3;
    const ushort* Bt = args.Bt[which];
    void* Cv = args.C[which];
    const int emode = args.emode[which];
    const int n0 = (bx & 7) * 128, m0 = by * 128;
    const int wm = w & 1, wn = w >> 1;

    f32x4 acc[4][4];
    const f32x4 fzero = {0.f, 0.f, 0.f, 0.f};
    #pragma unroll
    for (int i = 0; i < 4; i++)
        #pragma unroll
        for (int j = 0; j < 4; j++) acc[i][j] = fzero;

    const int srow = w * 32 + (lane >> 2);
    const int scol = (lane & 3) * 8;
    const ushort* ga  = A  + (size_t)(m0 + srow) * 1024 + scol;
    const ushort* ga2 = ga + 16 * 1024;
    const ushort* gb  = Bt + (size_t)(n0 + srow) * 1024 + scol;
    const ushort* gb2 = gb + 16 * 1024;
    const int lo1 = (w * 32) * 32;
    const int lo2 = (w * 32 + 16) * 32;

    // prologue: stage tile 0 into buffer 0 (4 loads/wave)
    gload16(ga, &As[0][lo1]);
    gload16(ga2, &As[0][lo2]);
    gload16(gb, &Bs[0][lo1]);
    gload16(gb2, &Bs[0][lo2]);

    int cur = 0, nxt = 1;
    for (int kt = 0; kt < 1024; kt += 32) {
        if (kt < 1024 - 32) {
            const int nk = kt + 32;
            gload16(ga + nk, &As[nxt][lo1]);
            gload16(ga2 + nk, &As[nxt][lo2]);
            gload16(gb + nk, &Bs[nxt][lo1]);
            gload16(gb2 + nk, &Bs[nxt][lo2]);
            // wait only for tile-cur's 4 loads; the 4 just-issued stay in flight
            asm volatile("s_waitcnt vmcnt(4)" ::: "memory");
        } else {
            asm volatile("s_waitcnt vmcnt(0)" ::: "memory");
        }
        __builtin_amdgcn_sched_barrier(0);
        __builtin_amdgcn_s_barrier();
        __builtin_amdgcn_sched_barrier(0);

        const ushort* Ac = As[cur];
        const ushort* Bc = Bs[cur];
        bf16x8 am[4], bn[4];
        #pragma unroll
        for (int i = 0; i < 4; i++)
            am[i] = *(const bf16x8*)&Ac[(wm * 64 + i * 16 + ln) * 32 + quad * 8];
        #pragma unroll
        for (int i = 0; i < 4; i++)
            bn[i] = *(const bf16x8*)&Bc[(wn * 64 + i * 16 + ln) * 32 + quad * 8];
        #pragma unroll
        for (int mi = 0; mi < 4; mi++)
            #pragma unroll
            for (int ni = 0; ni < 4; ni++)
                acc[mi][ni] = __builtin_amdgcn_mfma_f32_16x16x32_bf16(
                    am[mi], bn[ni], acc[mi][ni], 0, 0, 0);

        cur = nxt; nxt = nxt + 1; if (nxt == 3) nxt = 0;
    }

    #pragma unroll
    for (int mi = 0; mi < 4; mi++) {
        #pragma unroll
        for (int ni = 0; ni < 4; ni++) {
            const int row0 = m0 + wm * 64 + mi * 16 + quad * 4;
            const int e = wn * 64 + ni * 16 + ln;       // col within head
            const int col = n0 + e;
            if (emode == 5) {
                const int b = row0 >> 11, l0 = row0 & (LL - 1);
                ushort4 pk;
                pk.x = f2bf(acc[mi][ni][0]); pk.y = f2bf(acc[mi][ni][1]);
                pk.z = f2bf(acc[mi][ni][2]); pk.w = f2bf(acc[mi][ni][3]);
                *(ushort4*)&((ushort*)Cv)[((size_t)(b * 1024 + col)) * 2048 + l0] = pk;
                continue;
            }
            #pragma unroll
            for (int r = 0; r < 4; r++) {
                float v = acc[mi][ni][r];
                if (emode == 1 || emode == 2) {
                    float4 tt = tbl[(size_t)((row0 + r) & (LL - 1)) * 64 + (e >> 1)];
                    float cc = (emode == 1) ? tt.x : tt.z;
                    float ss = (emode == 1) ? tt.y : tt.w;
                    float partner = __shfl_xor(v, 1);
                    float rot = (e & 1) ? partner : -partner;
                    v = v * cc + rot * ss;
                } else if (emode == 3) {
                    v = v / (1.0f + expf(-v));
                }
                if (emode == 4)
                    ((float*)Cv)[(size_t)(row0 + r) * 1024 + col] = v;
                else
                    ((ushort*)Cv)[(size_t)(row0 + r) * 1024 + col] = f2bf(v);
            }
        }
    }
}

// ---------------------------------------------------------------------------
// Retention (MFMA, balanced) + FUSED GroupNorm/gate epilogue.
// Block z handles query blocks z and 31-z of its (b,h). Each block holds the
// full 128-dim v-range for its 64 rows -> mean/var via in-quad shfl reduce,
// affine + silu-gate applied in registers, Z written bf16 directly.
// XCD swizzle: all 16 x-blocks of one (b,h) land on one XCD (K/V set = 4MB).
// ---------------------------------------------------------------------------
__global__ __launch_bounds__(256) void ret_kernel(
    const ushort* __restrict__ Qb, const ushort* __restrict__ Kb,
    const ushort* __restrict__ Vt, const ushort* __restrict__ Gb,
    const float* __restrict__ gnw, const float* __restrict__ gnb,
    ushort* __restrict__ Z, Gammas gp)
{
    __shared__ __align__(16) ushort Ks[64 * 136];
    __shared__ __align__(16) ushort Vs[128 * 72];
    __shared__ __align__(16) ushort Ss[64 * 72];

    const int t = threadIdx.x;
    const int w = t >> 6, lane = t & 63, ln = lane & 15, quad = lane >> 4;

    // XCD-aware swizzle (512 blocks, 512%8==0 -> bijective):
    // xcd = gid%8 gets bh in [4*xcd, 4*xcd+3], all 16 x-blocks of each.
    const int gid = blockIdx.y * 16 + blockIdx.x;
    const int xcd = gid & 7, within = gid >> 3;
    const int bh = (xcd << 2) | (within >> 4);
    const int xb = within & 15;

    const int b = bh >> 3, h = bh & 7;
    const float lg2 = gp.lg2[h];
    const size_t qkbase = (size_t)b * LL * 1024 + (size_t)h * 128;
    const size_t vtbase = ((size_t)b * 1024 + h * 128) * 2048;

    // decay cutoff: skip chunks where max decay < 2^-34
    const int cap = (int)((34.0f / (-lg2) + 63.0f) * 0.015625f);

    float dmk[4], drr[4];
    #pragma unroll
    for (int kt = 0; kt < 4; kt++)
        dmk[kt] = exp2f(-(float)(kt * 16 + quad * 4) * lg2);
    #pragma unroll
    for (int r = 0; r < 4; r++)
        drr[r] = exp2f(-(float)r * lg2);

    // groupnorm affine params (cols identical for both segs)
    float gwv[8], gbv[8];
    #pragma unroll
    for (int vt = 0; vt < 8; vt++) {
        gwv[vt] = gnw[h * 128 + vt * 16 + ln];
        gbv[vt] = gnb[h * 128 + vt * 16 + ln];
    }

    // staging indices
    const int krow = t >> 4, kc = (t & 15) * 8;      // K: 4 x (16-row step)
    const int vrow = t >> 3, vc = (t & 7) * 8;       // V: 4 x (32-row step)

    for (int seg = 0; seg < 2; seg++) {
        const int qb = seg ? 31 - xb : xb;
        const int n0 = qb * 64;

        bf16x8 aq[4];
        #pragma unroll
        for (int ks = 0; ks < 4; ks++)
            aq[ks] = *(const bf16x8*)&Qb[qkbase + (size_t)(n0 + 16 * w + ln) * 1024
                                         + ks * 32 + quad * 8];
        f32x4 y[8];
        const f32x4 fzero = {0.f, 0.f, 0.f, 0.f};
        #pragma unroll
        for (int vt = 0; vt < 8; vt++) y[vt] = fzero;

        int cmin = qb - cap; if (cmin < 0) cmin = 0;

        uint4 kreg[4], vreg[4];
        {
            const int m0 = cmin * 64;
            #pragma unroll
            for (int i = 0; i < 4; i++)
                kreg[i] = *(const uint4*)&Kb[qkbase + (size_t)(m0 + krow + i * 16) * 1024 + kc];
            #pragma unroll
            for (int i = 0; i < 4; i++)
                vreg[i] = *(const uint4*)&Vt[vtbase + (size_t)(vrow + i * 32) * 2048 + m0 + vc];
        }

        for (int c = cmin; c <= qb; c++) {
            const int m0 = c * 64;
            __syncthreads();
            #pragma unroll
            for (int i = 0; i < 4; i++)
                *(uint4*)&Ks[(krow + i * 16) * 136 + kc] = kreg[i];
            #pragma unroll
            for (int i = 0; i < 4; i++)
                *(uint4*)&Vs[(vrow + i * 32) * 72 + vc] = vreg[i];
            __syncthreads();
            if (c < qb) {
                const int m1 = m0 + 64;
                #pragma unroll
                for (int i = 0; i < 4; i++)
                    kreg[i] = *(const uint4*)&Kb[qkbase + (size_t)(m1 + krow + i * 16) * 1024 + kc];
                #pragma unroll
                for (int i = 0; i < 4; i++)
                    vreg[i] = *(const uint4*)&Vt[vtbase + (size_t)(vrow + i * 32) * 2048 + m1 + vc];
            }

            // S^T blocks: mfma(bk, aq) -> lane holds S[n=16w+ln][m=kt*16+quad*4+r]
            f32x4 s4[4];
            #pragma unroll
            for (int kt = 0; kt < 4; kt++) s4[kt] = fzero;
            #pragma unroll
            for (int ks = 0; ks < 4; ks++) {
                #pragma unroll
                for (int kt = 0; kt < 4; kt++) {
                    bf16x8 bk = *(const bf16x8*)&Ks[(kt * 16 + ln) * 136 + ks * 32 + quad * 8];
                    s4[kt] = __builtin_amdgcn_mfma_f32_16x16x32_bf16(bk, aq[ks], s4[kt], 0, 0, 0);
                }
            }

            const float dq = exp2f((float)(n0 - m0 + 16 * w + ln) * lg2);
            if (c == qb) {
                #pragma unroll
                for (int kt = 0; kt < 4; kt++) {
                    const float db = dq * dmk[kt];
                    ushort4 pk;
                    pk.x = f2bf((kt * 16 + quad * 4 + 0 <= 16 * w + ln) ? s4[kt][0] * db * drr[0] : 0.f);
                    pk.y = f2bf((kt * 16 + quad * 4 + 1 <= 16 * w + ln) ? s4[kt][1] * db * drr[1] : 0.f);
                    pk.z = f2bf((kt * 16 + quad * 4 + 2 <= 16 * w + ln) ? s4[kt][2] * db * drr[2] : 0.f);
                    pk.w = f2bf((kt * 16 + quad * 4 + 3 <= 16 * w + ln) ? s4[kt][3] * db * drr[3] : 0.f);
                    *(ushort4*)&Ss[(16 * w + ln) * 72 + kt * 16 + quad * 4] = pk;
                }
            } else {
                #pragma unroll
                for (int kt = 0; kt < 4; kt++) {
                    const float db = dq * dmk[kt];
                    ushort4 pk;
                    pk.x = f2bf(s4[kt][0] * db * drr[0]);
                    pk.y = f2bf(s4[kt][1] * db * drr[1]);
                    pk.z = f2bf(s4[kt][2] * db * drr[2]);
                    pk.w = f2bf(s4[kt][3] * db * drr[3]);
                    *(ushort4*)&Ss[(16 * w + ln) * 72 + kt * 16 + quad * 4] = pk;
                }
            }

            // Y += S * V   (Ss rows are wave-private: no barrier needed)
            #pragma unroll
            for (int ks2 = 0; ks2 < 2; ks2++) {
                bf16x8 as = *(const bf16x8*)&Ss[(16 * w + ln) * 72 + ks2 * 32 + quad * 8];
                #pragma unroll
                for (int vt = 0; vt < 8; vt++) {
                    bf16x8 bv = *(const bf16x8*)&Vs[(vt * 16 + ln) * 72 + ks2 * 32 + quad * 8];
                    y[vt] = __builtin_amdgcn_mfma_f32_16x16x32_bf16(as, bv, y[vt], 0, 0, 0);
                }
            }
        }

        // fused GroupNorm + affine + gate epilogue (row = n0+16w+quad*4+r,
        // its 128 v-values live in the 16 ln-lanes of this quad x 8 vt regs)
        #pragma unroll
        for (int r = 0; r < 4; r++) {
            float s = 0.f, sq = 0.f;
            #pragma unroll
            for (int vt = 0; vt < 8; vt++) {
                float v = y[vt][r];
                s += v; sq += v * v;
            }
            #pragma unroll
            for (int off = 8; off >= 1; off >>= 1) {
                s  += __shfl_xor(s, off, 64);
                sq += __shfl_xor(sq, off, 64);
            }
            float mean = s * 0.0078125f;
            float var = sq * 0.0078125f - mean * mean;
            float rstd = rsqrtf(var + 1e-5f);
            const size_t row = (size_t)(b * LL + n0 + 16 * w + quad * 4 + r);
            #pragma unroll
            for (int vt = 0; vt < 8; vt++) {
                float gv = bf2f(Gb[row * 1024 + h * 128 + vt * 16 + ln]);
                float o = (y[vt][r] - mean) * rstd * gwv[vt] + gbv[vt];
                Z[row * 1024 + h * 128 + vt * 16 + ln] = f2bf(o * gv);
            }
        }
    }
}

// ---------------------------------------------------------------------------
extern "C" void kernel_launch(void* const* d_in, const int* in_sizes, int n_in,
                              void* d_out, int out_size, void* d_ws, size_t ws_size,
                              hipStream_t stream) {
    const float* X   = (const float*)d_in[0];
    const float* Wq  = (const float*)d_in[1];
    const float* Wk  = (const float*)d_in[2];
    const float* Wv  = (const float*)d_in[3];
    const float* Wg  = (const float*)d_in[4];
    const float* Wo  = (const float*)d_in[5];
    const float* gnw = (const float*)d_in[6];
    const float* gnb = (const float*)d_in[7];
    float* out = (float*)d_out;

    const size_t MB = 1u << 20;
    char* base = (char*)d_ws;
    float4* tbl = (float4*)base;                        // 2 MB
    ushort* Xb  = (ushort*)(base + 2 * MB);             // 16 MB
    ushort* Wqt = (ushort*)(base + 18 * MB);
    ushort* Wkt = (ushort*)(base + 20 * MB);
    ushort* Wvt = (ushort*)(base + 22 * MB);
    ushort* Wgt = (ushort*)(base + 24 * MB);
    ushort* Wot = (ushort*)(base + 26 * MB);
    ushort* Qb  = (ushort*)(base + 28 * MB);            // 16 MB
    ushort* Kb  = (ushort*)(base + 44 * MB);            // 16 MB
    ushort* Gb  = (ushort*)(base + 60 * MB);            // 16 MB
    ushort* Vt  = (ushort*)(base + 76 * MB);            // 16 MB
    ushort* Zb  = (ushort*)(base + 92 * MB);            // 16 MB (own buffer:
                                                        // ret reads Qb concurrently)

    Gammas gp;
    for (int h = 0; h < 8; h++) {
        double lin = log(1.0 / 32.0) +
                     (log(1.0 / 512.0) - log(1.0 / 32.0)) * (double)h / 7.0;
        float gamma = 1.0f - expf((float)lin);
        gp.lg2[h] = log2f(gamma);
    }

    xpos_table_kernel<<<(LL * 64) / 256, 256, 0, stream>>>(tbl);
    cast_kernel<<<MM * 1024 / 1024, 256, 0, stream>>>(X, Xb);

    dim3 wgrid(16, 16);
    wtrans_kernel<<<wgrid, 256, 0, stream>>>(Wq, Wqt, 1);
    wtrans_kernel<<<wgrid, 256, 0, stream>>>(Wk, Wkt, 1);
    wtrans_kernel<<<wgrid, 256, 0, stream>>>(Wv, Wvt, 1);
    wtrans_kernel<<<wgrid, 256, 0, stream>>>(Wg, Wgt, 0);
    wtrans_kernel<<<wgrid, 256, 0, stream>>>(Wo, Wot, 0);

    // fused Q/K/V/G projections (V written directly transposed into Vt)
    MMArgs qa;
    qa.Bt[0] = Wqt; qa.Bt[1] = Wkt; qa.Bt[2] = Wvt; qa.Bt[3] = Wgt;
    qa.C[0] = Qb;   qa.C[1] = Kb;   qa.C[2] = Vt;   qa.C[3] = Gb;
    qa.emode[0] = 1; qa.emode[1] = 2; qa.emode[2] = 5; qa.emode[3] = 3;
    mm_kernel<<<dim3(32, 64), 256, 0, stream>>>(Xb, qa, tbl);

    // retention + fused groupnorm/gate -> Zb (bf16)
    ret_kernel<<<dim3(16, 32), 256, 0, stream>>>(Qb, Kb, Vt, Gb, gnw, gnb, Zb, gp);

    MMArgs oa;
    oa.Bt[0] = Wot; oa.Bt[1] = Wot; oa.Bt[2] = Wot; oa.Bt[3] = Wot;
    oa.C[0] = out;  oa.C[1] = out;  oa.C[2] = out;  oa.C[3] = out;
    oa.emode[0] = 4; oa.emode[1] = 4; oa.emode[2] = 4; oa.emode[3] = 4;
    mm_kernel<<<dim3(8, 64), 256, 0, stream>>>(Zb, oa, tbl);
}

// Round 5
// 394.087 us; speedup vs baseline: 1.3100x; 1.2478x over previous
//
#include <hip/hip_runtime.h>
#include <cmath>

#define BB 4
#define LL 2048
#define DD 1024
#define HH 8
#define MM (BB * LL)   // 8192 rows

struct Gammas { float lg2[8]; };
struct MMArgs { const ushort* Bt[4]; void* C[4]; void* C2[4]; int emode[4]; };

typedef __attribute__((ext_vector_type(8))) short bf16x8;
typedef __attribute__((ext_vector_type(4))) float f32x4;

__device__ __forceinline__ ushort f2bf(float f) {
    uint u = __builtin_bit_cast(uint, f);
    uint r = (u + 0x7fffu + ((u >> 16) & 1u)) >> 16;
    return (ushort)r;
}
__device__ __forceinline__ float bf2f(ushort h) {
    uint u = ((uint)h) << 16;
    return __builtin_bit_cast(float, u);
}
__device__ __forceinline__ void gload16(const void* g, void* l) {
    __builtin_amdgcn_global_load_lds((const __attribute__((address_space(1))) void*)g,
                                     (__attribute__((address_space(3))) void*)l, 16, 0, 0);
}

// ---------------------------------------------------------------------------
// xpos table: tbl[l*64 + i] = {cos*scale, sin*scale, cos/scale, sin/scale}
// ---------------------------------------------------------------------------
__global__ void xpos_table_kernel(float4* __restrict__ tbl) {
    int tid = blockIdx.x * blockDim.x + threadIdx.x;
    if (tid >= LL * 64) return;
    int l = tid >> 6, i = tid & 63;
    float inv = powf(10000.0f, -(float)i / 64.0f);
    float ang = (float)l * inv;
    float s = sinf(ang), c = cosf(ang);
    float base = (2.0f * (float)i + 51.2f) / 179.2f;
    float sc = powf(base, (float)l / 512.0f);
    tbl[tid] = make_float4(c * sc, s * sc, c / sc, s / sc);
}

__global__ __launch_bounds__(256) void cast_kernel(const float* __restrict__ X,
                                                   ushort* __restrict__ Xb) {
    int i = (blockIdx.x * 256 + threadIdx.x) * 4;
    float4 v = *(const float4*)&X[i];
    ushort4 o;
    o.x = f2bf(v.x); o.y = f2bf(v.y); o.z = f2bf(v.z); o.w = f2bf(v.w);
    *(ushort4*)&Xb[i] = o;
}

// ---------------------------------------------------------------------------
// Weight transpose+cast: W[k][n] (flat or per-head (h,d,e)) -> Wt[n][k] bf16
// ---------------------------------------------------------------------------
__global__ __launch_bounds__(256) void wtrans_kernel(const float* __restrict__ W,
                                                     ushort* __restrict__ Wt, int perhead) {
    __shared__ float T[64][68];
    const int k0 = blockIdx.y * 64, n0 = blockIdx.x * 64;
    const int t = threadIdx.x;
    for (int f = t; f < 64 * 16; f += 256) {
        int kk = f >> 4, s = f & 15;
        int n = n0 + s * 4;
        size_t src = perhead ? (size_t)(n >> 7) * 131072 + (size_t)(k0 + kk) * 128 + (n & 127)
                             : (size_t)(k0 + kk) * 1024 + n;
        *(float4*)&T[kk][s * 4] = *(const float4*)&W[src];
    }
    __syncthreads();
    for (int f = t; f < 64 * 8; f += 256) {
        int n = f >> 3, s = f & 7;
        __align__(16) ushort tmp[8];
        #pragma unroll
        for (int j = 0; j < 8; j++) tmp[j] = f2bf(T[s * 8 + j][n]);
        *(uint4*)&Wt[(size_t)(n0 + n) * 1024 + k0 + s * 8] = *(uint4*)tmp;
    }
}

// ---------------------------------------------------------------------------
// bf16 MFMA GEMM (round-2 proven config): 128x128 tile, BK=32, 2-phase
// double-buffered LDS, one __syncthreads per K-step.
// emode: 1 xpos up->bf16, 2 xpos down->bf16, 3 silu->bf16, 4 plain->fp32,
//        5 V-transposed store (Vt[b][v][l]), 6 xpos down -> row-major Kb AND
//        transposed K~t (C2).
// ---------------------------------------------------------------------------
__global__ __launch_bounds__(256) void mm_kernel(
    const ushort* __restrict__ A, MMArgs args, const float4* __restrict__ tbl)
{
    __shared__ __align__(16) ushort As[2][128 * 32];
    __shared__ __align__(16) ushort Bs[2][128 * 32];
    const int t = threadIdx.x;
    const int w = t >> 6, lane = t & 63;
    const int ln = lane & 15, quad = lane >> 4;
    const int which = blockIdx.x >> 3;
    const ushort* Bt = args.Bt[which];
    void* Cv = args.C[which];
    void* Cv2 = args.C2[which];
    const int emode = args.emode[which];
    const int n0 = (blockIdx.x & 7) * 128, m0 = blockIdx.y * 128;
    const int wm = w & 1, wn = w >> 1;

    f32x4 acc[4][4];
    const f32x4 fzero = {0.f, 0.f, 0.f, 0.f};
    #pragma unroll
    for (int i = 0; i < 4; i++)
        #pragma unroll
        for (int j = 0; j < 4; j++) acc[i][j] = fzero;

    const int srow = w * 32 + (lane >> 2);
    const int scol = (lane & 3) * 8;
    const ushort* ga  = A  + (size_t)(m0 + srow) * 1024 + scol;
    const ushort* ga2 = ga + 16 * 1024;
    const ushort* gb  = Bt + (size_t)(n0 + srow) * 1024 + scol;
    const ushort* gb2 = gb + 16 * 1024;
    const int lo1 = (w * 32) * 32;
    const int lo2 = (w * 32 + 16) * 32;

    gload16(ga, &As[0][lo1]);
    gload16(ga2, &As[0][lo2]);
    gload16(gb, &Bs[0][lo1]);
    gload16(gb2, &Bs[0][lo2]);
    __syncthreads();

    for (int kt = 0; kt < 1024; kt += 32) {
        const int cur = (kt >> 5) & 1;
        if (kt < 1024 - 32) {
            const int nk = kt + 32;
            gload16(ga + nk, &As[cur ^ 1][lo1]);
            gload16(ga2 + nk, &As[cur ^ 1][lo2]);
            gload16(gb + nk, &Bs[cur ^ 1][lo1]);
            gload16(gb2 + nk, &Bs[cur ^ 1][lo2]);
        }
        bf16x8 am[4], bn[4];
        #pragma unroll
        for (int i = 0; i < 4; i++)
            am[i] = *(const bf16x8*)&As[cur][(wm * 64 + i * 16 + ln) * 32 + quad * 8];
        #pragma unroll
        for (int i = 0; i < 4; i++)
            bn[i] = *(const bf16x8*)&Bs[cur][(wn * 64 + i * 16 + ln) * 32 + quad * 8];
        #pragma unroll
        for (int mi = 0; mi < 4; mi++)
            #pragma unroll
            for (int ni = 0; ni < 4; ni++)
                acc[mi][ni] = __builtin_amdgcn_mfma_f32_16x16x32_bf16(
                    am[mi], bn[ni], acc[mi][ni], 0, 0, 0);
        __syncthreads();
    }

    #pragma unroll
    for (int mi = 0; mi < 4; mi++) {
        #pragma unroll
        for (int ni = 0; ni < 4; ni++) {
            const int row0 = m0 + wm * 64 + mi * 16 + quad * 4;
            const int e = wn * 64 + ni * 16 + ln;       // col within head
            const int col = n0 + e;
            if (emode == 5) {
                const int b = row0 >> 11, l0 = row0 & (LL - 1);
                ushort4 pk;
                pk.x = f2bf(acc[mi][ni][0]); pk.y = f2bf(acc[mi][ni][1]);
                pk.z = f2bf(acc[mi][ni][2]); pk.w = f2bf(acc[mi][ni][3]);
                *(ushort4*)&((ushort*)Cv)[((size_t)(b * 1024 + col)) * 2048 + l0] = pk;
                continue;
            }
            float vv[4];
            #pragma unroll
            for (int r = 0; r < 4; r++) {
                float v = acc[mi][ni][r];
                if (emode == 1 || emode == 2 || emode == 6) {
                    float4 tt = tbl[(size_t)((row0 + r) & (LL - 1)) * 64 + (e >> 1)];
                    float cc = (emode == 1) ? tt.x : tt.z;
                    float ss = (emode == 1) ? tt.y : tt.w;
                    float partner = __shfl_xor(v, 1);
                    float rot = (e & 1) ? partner : -partner;
                    v = v * cc + rot * ss;
                } else if (emode == 3) {
                    v = v / (1.0f + expf(-v));
                }
                vv[r] = v;
                if (emode == 4)
                    ((float*)Cv)[(size_t)(row0 + r) * 1024 + col] = v;
                else
                    ((ushort*)Cv)[(size_t)(row0 + r) * 1024 + col] = f2bf(v);
            }
            if (emode == 6) {
                const int b = row0 >> 11, l0 = row0 & (LL - 1);
                ushort4 pk;
                pk.x = f2bf(vv[0]); pk.y = f2bf(vv[1]);
                pk.z = f2bf(vv[2]); pk.w = f2bf(vv[3]);
                *(ushort4*)&((ushort*)Cv2)[((size_t)(b * 1024 + col)) * 2048 + l0] = pk;
            }
        }
    }
}

// ---------------------------------------------------------------------------
// R1: per-chunk local state L_c^T[v][d] = sum_m gamma^{63-m} K~[m][d] V[m][v],
// one block per (bh, c). MFMA over m (k=64), LDS-bounced coalesced bf16 store.
// ---------------------------------------------------------------------------
__global__ __launch_bounds__(256) void state_kernel(
    const ushort* __restrict__ Ktb, const ushort* __restrict__ Vt,
    ushort* __restrict__ Sb, Gammas gp)
{
    __shared__ __align__(16) ushort shbuf[2 * 128 * 72];   // Ktl | Vwl, reused as Lsh
    ushort* Ktl = shbuf;
    ushort* Vwl = shbuf + 128 * 72;

    const int t = threadIdx.x;
    const int w = t >> 6, lane = t & 63, ln = lane & 15, quad = lane >> 4;
    const int c = blockIdx.x, bh = blockIdx.y;
    const int b = bh >> 3, h = bh & 7;
    const float lg2 = gp.lg2[h];
    const size_t tbase = ((size_t)b * 1024 + h * 128) * 2048 + (size_t)c * 64;

    // stage: thread t -> row = t>>1 (0..127), elems [soff, soff+32)
    const int sr = t >> 1, soff = (t & 1) * 32;
    #pragma unroll
    for (int j = 0; j < 4; j++)
        *(uint4*)&Ktl[sr * 72 + soff + j * 8] =
            *(const uint4*)&Ktb[tbase + (size_t)sr * 2048 + soff + j * 8];
    #pragma unroll
    for (int j = 0; j < 4; j++) {
        uint4 raw = *(const uint4*)&Vt[tbase + (size_t)sr * 2048 + soff + j * 8];
        ushort* rp = (ushort*)&raw;
        __align__(16) ushort tmp[8];
        #pragma unroll
        for (int jj = 0; jj < 8; jj++) {
            int m = soff + j * 8 + jj;
            tmp[jj] = f2bf(bf2f(rp[jj]) * exp2f(lg2 * (float)(63 - m)));
        }
        *(uint4*)&Vwl[sr * 72 + soff + j * 8] = *(uint4*)tmp;
    }
    __syncthreads();

    const int wm = w & 1, wn = w >> 1;
    f32x4 acc[4][4];
    const f32x4 fzero = {0.f, 0.f, 0.f, 0.f};
    #pragma unroll
    for (int i = 0; i < 4; i++)
        #pragma unroll
        for (int j = 0; j < 4; j++) acc[i][j] = fzero;

    #pragma unroll
    for (int ks = 0; ks < 2; ks++) {
        bf16x8 am[4], bn[4];
        #pragma unroll
        for (int mi = 0; mi < 4; mi++)
            am[mi] = *(const bf16x8*)&Ktl[(wm * 64 + mi * 16 + ln) * 72 + ks * 32 + quad * 8];
        #pragma unroll
        for (int ni = 0; ni < 4; ni++)
            bn[ni] = *(const bf16x8*)&Vwl[(wn * 64 + ni * 16 + ln) * 72 + ks * 32 + quad * 8];
        #pragma unroll
        for (int mi = 0; mi < 4; mi++)
            #pragma unroll
            for (int ni = 0; ni < 4; ni++)
                acc[mi][ni] = __builtin_amdgcn_mfma_f32_16x16x32_bf16(
                    am[mi], bn[ni], acc[mi][ni], 0, 0, 0);
    }
    __syncthreads();

    // bounce: Lsh[v][136] (pad -> 16B-aligned rows), then coalesced store
    ushort* Lsh = shbuf;
    #pragma unroll
    for (int mi = 0; mi < 4; mi++) {
        #pragma unroll
        for (int ni = 0; ni < 4; ni++) {
            const int d0 = wm * 64 + mi * 16 + quad * 4;
            const int v = wn * 64 + ni * 16 + ln;
            ushort4 pk;
            pk.x = f2bf(acc[mi][ni][0]); pk.y = f2bf(acc[mi][ni][1]);
            pk.z = f2bf(acc[mi][ni][2]); pk.w = f2bf(acc[mi][ni][3]);
            *(ushort4*)&Lsh[v * 136 + d0] = pk;
        }
    }
    __syncthreads();
    ushort* dst = Sb + (size_t)(bh * 32 + c) * 128 * 128;
    const int orow = t >> 1, ooff = (t & 1) * 64;
    #pragma unroll
    for (int j = 0; j < 8; j++)
        *(uint4*)&dst[(size_t)orow * 128 + ooff + j * 8] =
            *(uint4*)&Lsh[orow * 136 + ooff + j * 8];
}

// ---------------------------------------------------------------------------
// R2: in-place scan over chunks: slot c-1 <- P_c = g64*P_{c-1} + L_{c-1}.
// RMW same address; store value depends on load -> ordering by data dep.
// ---------------------------------------------------------------------------
__global__ __launch_bounds__(256) void scan_kernel(ushort* __restrict__ Sb, Gammas gp)
{
    const int t = threadIdx.x;
    const int vb = blockIdx.x, bh = blockIdx.y;
    const int h = bh & 7;
    const float g64 = exp2f(64.0f * gp.lg2[h]);
    const int v = vb * 16 + (t >> 4);
    const int d0 = (t & 15) * 8;

    float acc[8];
    #pragma unroll
    for (int j = 0; j < 8; j++) acc[j] = 0.f;

    for (int c = 1; c < 32; c++) {
        ushort* p = Sb + ((size_t)(bh * 32 + (c - 1)) * 128 + v) * 128 + d0;
        uint4 lv = *(const uint4*)p;
        ushort* lp = (ushort*)&lv;
        __align__(16) ushort o[8];
        #pragma unroll
        for (int j = 0; j < 8; j++) {
            acc[j] = g64 * acc[j] + bf2f(lp[j]);
            o[j] = f2bf(acc[j]);
        }
        *(uint4*)p = *(uint4*)o;
    }
}

// ---------------------------------------------------------------------------
// R3: Y(chunk c) = gamma^{r+1} * Q~ . P_c  +  intra-chunk retention,
// fused GroupNorm + affine + silu-gate epilogue. One block per (bh, c).
// ---------------------------------------------------------------------------
__global__ __launch_bounds__(256) void ret2_kernel(
    const ushort* __restrict__ Qb, const ushort* __restrict__ Kb,
    const ushort* __restrict__ Vt, const ushort* __restrict__ Pt,
    const ushort* __restrict__ Gb,
    const float* __restrict__ gnw, const float* __restrict__ gnb,
    ushort* __restrict__ Z, Gammas gp)
{
    __shared__ __align__(16) ushort Ks[64 * 136];
    __shared__ __align__(16) ushort Vs[128 * 72];
    __shared__ __align__(16) ushort Ss[64 * 72];
    __shared__ __align__(16) ushort Ps[128 * 136];

    const int t = threadIdx.x;
    const int w = t >> 6, lane = t & 63, ln = lane & 15, quad = lane >> 4;
    const int c = blockIdx.x, bh = blockIdx.y;
    const int b = bh >> 3, h = bh & 7;
    const float lg2 = gp.lg2[h];
    const size_t qkbase = (size_t)b * LL * 1024 + (size_t)h * 128;
    const size_t vtbase = ((size_t)b * 1024 + h * 128) * 2048;
    const int n0 = c * 64;

    float dmk[4], drr[4];
    #pragma unroll
    for (int kt = 0; kt < 4; kt++)
        dmk[kt] = exp2f(-(float)(kt * 16 + quad * 4) * lg2);
    #pragma unroll
    for (int r = 0; r < 4; r++)
        drr[r] = exp2f(-(float)r * lg2);

    float gwv[8], gbv[8];
    #pragma unroll
    for (int vt = 0; vt < 8; vt++) {
        gwv[vt] = gnw[h * 128 + vt * 16 + ln];
        gbv[vt] = gnb[h * 128 + vt * 16 + ln];
    }

    // stage K, V (own chunk) and P_c (slot c-1; skip for c==0)
    const int krow = t >> 4, kc = (t & 15) * 8;
    const int vrow = t >> 3, vc = (t & 7) * 8;
    #pragma unroll
    for (int i = 0; i < 4; i++)
        *(uint4*)&Ks[(krow + i * 16) * 136 + kc] =
            *(const uint4*)&Kb[qkbase + (size_t)(n0 + krow + i * 16) * 1024 + kc];
    #pragma unroll
    for (int i = 0; i < 4; i++)
        *(uint4*)&Vs[(vrow + i * 32) * 72 + vc] =
            *(const uint4*)&Vt[vtbase + (size_t)(vrow + i * 32) * 2048 + n0 + vc];
    if (c > 0) {
        const ushort* psrc = Pt + (size_t)(bh * 32 + (c - 1)) * 128 * 128;
        const int pr = t >> 1, poff = (t & 1) * 64;
        #pragma unroll
        for (int j = 0; j < 8; j++)
            *(uint4*)&Ps[pr * 136 + poff + j * 8] =
                *(const uint4*)&psrc[(size_t)pr * 128 + poff + j * 8];
    }

    bf16x8 aq[4];
    #pragma unroll
    for (int ks = 0; ks < 4; ks++)
        aq[ks] = *(const bf16x8*)&Qb[qkbase + (size_t)(n0 + 16 * w + ln) * 1024
                                     + ks * 32 + quad * 8];
    f32x4 y[8];
    const f32x4 fzero = {0.f, 0.f, 0.f, 0.f};
    #pragma unroll
    for (int vt = 0; vt < 8; vt++) y[vt] = fzero;

    __syncthreads();

    // inter: y = Q~ . P_c, then scale row by gamma^{r_local+1}
    if (c > 0) {
        #pragma unroll
        for (int ks = 0; ks < 4; ks++) {
            #pragma unroll
            for (int vt = 0; vt < 8; vt++) {
                bf16x8 bp = *(const bf16x8*)&Ps[(vt * 16 + ln) * 136 + ks * 32 + quad * 8];
                y[vt] = __builtin_amdgcn_mfma_f32_16x16x32_bf16(aq[ks], bp, y[vt], 0, 0, 0);
            }
        }
        #pragma unroll
        for (int rr = 0; rr < 4; rr++) {
            const float sc = exp2f(lg2 * (float)(16 * w + quad * 4 + rr + 1));
            #pragma unroll
            for (int vt = 0; vt < 8; vt++) y[vt][rr] *= sc;
        }
    }

    // intra: S^T via mfma(bk, aq), masked + decayed, bf16 -> Ss
    f32x4 s4[4];
    #pragma unroll
    for (int kt = 0; kt < 4; kt++) s4[kt] = fzero;
    #pragma unroll
    for (int ks = 0; ks < 4; ks++) {
        #pragma unroll
        for (int kt = 0; kt < 4; kt++) {
            bf16x8 bk = *(const bf16x8*)&Ks[(kt * 16 + ln) * 136 + ks * 32 + quad * 8];
            s4[kt] = __builtin_amdgcn_mfma_f32_16x16x32_bf16(bk, aq[ks], s4[kt], 0, 0, 0);
        }
    }
    const float dq = exp2f((float)(16 * w + ln) * lg2);
    #pragma unroll
    for (int kt = 0; kt < 4; kt++) {
        const float db = dq * dmk[kt];
        ushort4 pk;
        pk.x = f2bf((kt * 16 + quad * 4 + 0 <= 16 * w + ln) ? s4[kt][0] * db * drr[0] : 0.f);
        pk.y = f2bf((kt * 16 + quad * 4 + 1 <= 16 * w + ln) ? s4[kt][1] * db * drr[1] : 0.f);
        pk.z = f2bf((kt * 16 + quad * 4 + 2 <= 16 * w + ln) ? s4[kt][2] * db * drr[2] : 0.f);
        pk.w = f2bf((kt * 16 + quad * 4 + 3 <= 16 * w + ln) ? s4[kt][3] * db * drr[3] : 0.f);
        *(ushort4*)&Ss[(16 * w + ln) * 72 + kt * 16 + quad * 4] = pk;
    }
    // y += S * V  (Ss rows wave-private)
    #pragma unroll
    for (int ks2 = 0; ks2 < 2; ks2++) {
        bf16x8 as = *(const bf16x8*)&Ss[(16 * w + ln) * 72 + ks2 * 32 + quad * 8];
        #pragma unroll
        for (int vt = 0; vt < 8; vt++) {
            bf16x8 bv = *(const bf16x8*)&Vs[(vt * 16 + ln) * 72 + ks2 * 32 + quad * 8];
            y[vt] = __builtin_amdgcn_mfma_f32_16x16x32_bf16(as, bv, y[vt], 0, 0, 0);
        }
    }

    // fused GroupNorm + affine + gate
    #pragma unroll
    for (int r = 0; r < 4; r++) {
        float s = 0.f, sq = 0.f;
        #pragma unroll
        for (int vt = 0; vt < 8; vt++) {
            float v = y[vt][r];
            s += v; sq += v * v;
        }
        #pragma unroll
        for (int off = 8; off >= 1; off >>= 1) {
            s  += __shfl_xor(s, off, 64);
            sq += __shfl_xor(sq, off, 64);
        }
        float mean = s * 0.0078125f;
        float var = sq * 0.0078125f - mean * mean;
        float rstd = rsqrtf(var + 1e-5f);
        const size_t row = (size_t)(b * LL + n0 + 16 * w + quad * 4 + r);
        #pragma unroll
        for (int vt = 0; vt < 8; vt++) {
            float gv = bf2f(Gb[row * 1024 + h * 128 + vt * 16 + ln]);
            float o = (y[vt][r] - mean) * rstd * gwv[vt] + gbv[vt];
            Z[row * 1024 + h * 128 + vt * 16 + ln] = f2bf(o * gv);
        }
    }
}

// ---------------------------------------------------------------------------
extern "C" void kernel_launch(void* const* d_in, const int* in_sizes, int n_in,
                              void* d_out, int out_size, void* d_ws, size_t ws_size,
                              hipStream_t stream) {
    const float* X   = (const float*)d_in[0];
    const float* Wq  = (const float*)d_in[1];
    const float* Wk  = (const float*)d_in[2];
    const float* Wv  = (const float*)d_in[3];
    const float* Wg  = (const float*)d_in[4];
    const float* Wo  = (const float*)d_in[5];
    const float* gnw = (const float*)d_in[6];
    const float* gnb = (const float*)d_in[7];
    float* out = (float*)d_out;

    const size_t MB = 1u << 20;
    char* base = (char*)d_ws;
    // Sb (32 MB, 0-32) overlays tbl/Xb/Wq..Wg, which die after the QKVG mm.
    ushort* Sb  = (ushort*)base;                        // 0-32  (L then P, bf16)
    float4* tbl = (float4*)base;                        // 0-2
    ushort* Xb  = (ushort*)(base + 2 * MB);             // 2-18
    ushort* Wqt = (ushort*)(base + 18 * MB);
    ushort* Wkt = (ushort*)(base + 20 * MB);
    ushort* Wvt = (ushort*)(base + 22 * MB);
    ushort* Wgt = (ushort*)(base + 24 * MB);
    ushort* Wot = (ushort*)(base + 32 * MB);            // 32-34
    ushort* Qb  = (ushort*)(base + 34 * MB);            // 34-50
    ushort* Kb  = (ushort*)(base + 50 * MB);            // 50-66
    ushort* Gb  = (ushort*)(base + 66 * MB);            // 66-82
    ushort* Vt  = (ushort*)(base + 82 * MB);            // 82-98
    ushort* Ktb = (ushort*)(base + 98 * MB);            // 98-114 (dead after R1)
    ushort* Zb  = (ushort*)(base + 98 * MB);            // reuses Ktb region in R3+

    Gammas gp;
    for (int h = 0; h < 8; h++) {
        double lin = log(1.0 / 32.0) +
                     (log(1.0 / 512.0) - log(1.0 / 32.0)) * (double)h / 7.0;
        float gamma = 1.0f - expf((float)lin);
        gp.lg2[h] = log2f(gamma);
    }

    xpos_table_kernel<<<(LL * 64) / 256, 256, 0, stream>>>(tbl);
    cast_kernel<<<MM * 1024 / 1024, 256, 0, stream>>>(X, Xb);

    dim3 wgrid(16, 16);
    wtrans_kernel<<<wgrid, 256, 0, stream>>>(Wq, Wqt, 1);
    wtrans_kernel<<<wgrid, 256, 0, stream>>>(Wk, Wkt, 1);
    wtrans_kernel<<<wgrid, 256, 0, stream>>>(Wv, Wvt, 1);
    wtrans_kernel<<<wgrid, 256, 0, stream>>>(Wg, Wgt, 0);
    wtrans_kernel<<<wgrid, 256, 0, stream>>>(Wo, Wot, 0);

    // fused Q/K/V/G projections; K emits row-major Kb AND transposed K~t
    MMArgs qa;
    qa.Bt[0] = Wqt; qa.Bt[1] = Wkt; qa.Bt[2] = Wvt; qa.Bt[3] = Wgt;
    qa.C[0] = Qb;   qa.C[1] = Kb;   qa.C[2] = Vt;   qa.C[3] = Gb;
    qa.C2[0] = nullptr; qa.C2[1] = Ktb; qa.C2[2] = nullptr; qa.C2[3] = nullptr;
    qa.emode[0] = 1; qa.emode[1] = 6; qa.emode[2] = 5; qa.emode[3] = 3;
    mm_kernel<<<dim3(32, 64), 256, 0, stream>>>(Xb, qa, tbl);

    // chunked-recurrent retention: local states -> scan -> per-chunk output
    state_kernel<<<dim3(32, 32), 256, 0, stream>>>(Ktb, Vt, Sb, gp);
    scan_kernel<<<dim3(8, 32), 256, 0, stream>>>(Sb, gp);
    ret2_kernel<<<dim3(32, 32), 256, 0, stream>>>(Qb, Kb, Vt, Sb, Gb,
                                                  gnw, gnb, Zb, gp);

    MMArgs oa;
    oa.Bt[0] = Wot; oa.Bt[1] = Wot; oa.Bt[2] = Wot; oa.Bt[3] = Wot;
    oa.C[0] = out;  oa.C[1] = out;  oa.C[2] = out;  oa.C[3] = out;
    oa.C2[0] = nullptr; oa.C2[1] = nullptr; oa.C2[2] = nullptr; oa.C2[3] = nullptr;
    oa.emode[0] = 4; oa.emode[1] = 4; oa.emode[2] = 4; oa.emode[3] = 4;
    mm_kernel<<<dim3(8, 64), 256, 0, stream>>>(Zb, oa, tbl);
}